// Round 1
// 452.084 us; speedup vs baseline: 1.3664x; 1.3664x over previous
//
#include <hip/hip_runtime.h>

#define NB 8
#define NC 512
#define NQ 64
#define NN 9216
#define FEPS 1e-6f

typedef __attribute__((ext_vector_type(8))) short s16x8;
typedef __attribute__((ext_vector_type(4))) float f32x4;

// workspace layout (floats)
static const size_t OFF_Q    = 0;                                  // Qt fp32 [B][64][N]
static const size_t OFF_KT   = OFF_Q + (size_t)NB * NQ * NN;       // Kt bf16 [B][64][N] (uses half the region)
static const size_t OFF_KSUM = OFF_KT + (size_t)NB * NQ * NN;      // [B][64]
static const size_t OFF_XSUM = OFF_KSUM + (size_t)NB * NQ;         // [B][512]
static const size_t OFF_M1   = OFF_XSUM + (size_t)NB * NC;         // [B][64][512]
static const size_t OFF_M2   = OFF_M1 + (size_t)NB * NQ * NC;      // [B][64][512]
static const size_t OFF_VSUM = OFF_M2 + (size_t)NB * NQ * NC;      // [B][512]
static const size_t OFF_WB   = OFF_VSUM + (size_t)NB * NC;         // bf16 [128][512] = 32768 floats

__device__ __forceinline__ void load_lds16(const void* g, void* l) {
    __builtin_amdgcn_global_load_lds((const __attribute__((address_space(1))) void*)g,
                                     (__attribute__((address_space(3))) void*)l, 16, 0, 0);
}

__device__ __forceinline__ unsigned cvt_pk_bf16(float lo, float hi) {
    unsigned r;
    asm("v_cvt_pk_bf16_f32 %0, %1, %2" : "=v"(r) : "v"(lo), "v"(hi));
    return r;
}

__device__ __forceinline__ unsigned short f2bf(float f) {
    union { float f; unsigned u; } a; a.f = f;
    unsigned r = a.u + 0x7FFFu + ((a.u >> 16) & 1u);
    return (unsigned short)(r >> 16);
}

// -------- one-time weight conversion: Wb[128][512] bf16, rows 0-63 = wq, 64-127 = wk --------
__global__ void prep_w_kernel(const float* __restrict__ wq, const float* __restrict__ wk,
                              unsigned short* __restrict__ Wb) {
    const int idx = blockIdx.x * 256 + threadIdx.x;
#pragma unroll
    for (int k = 0; k < 4; ++k) {
        const int f4 = idx + k * 4096;  // float4 index, 0..16383
        const float* src = (f4 < 8192) ? wq : wk;
        const float4 v = *(const float4*)&src[(size_t)(f4 & 8191) * 4];
        uint2 u;
        u.x = cvt_pk_bf16(v.x, v.y);
        u.y = cvt_pk_bf16(v.z, v.w);
        *(uint2*)&Wb[(size_t)f4 * 4] = u;
    }
}

// -------- Q/K projection via bf16 MFMA + bias + L2 normalize + ksum --------
// grid (144, 8), block 256 (4 waves). Per block: 128 outputs (64 Q + 64 K) x 64 positions.
// Wave w owns output rows [32w, 32w+32). C layout (m89): col=lane&15 (pos), row=4*(lane>>4)+reg.
// LDS tiles XOR-swizzled (ushort col ^= (row&7)<<3); global_load_lds dest linear, swizzle in src addr.
__launch_bounds__(256, 3)
__global__ void qk_mfma_kernel(const float* __restrict__ x,
                               const unsigned short* __restrict__ Wb,
                               const float* __restrict__ bq, const float* __restrict__ bk,
                               float* __restrict__ Qt, unsigned short* __restrict__ Ktb,
                               float* __restrict__ ksum) {
    __shared__ __align__(16) unsigned short WX[12672];  // Ws[128*64] | Xs[64*64]; epilogue: epQ f32[64*65] | epK u16[64*68]
    __shared__ float ssqL[4][64];
    unsigned short* Ws = WX;           // [128][64]
    unsigned short* Xs = WX + 8192;    // [64][64]
    const int t = threadIdx.x;
    const int w = t >> 6, lane = t & 63;
    const int g = lane >> 4, i16 = lane & 15;
    const int b = blockIdx.y;
    const int n0 = blockIdx.x * 64;
    const int srow = (w << 3) + (lane >> 3);
    const int sslot = lane & 7;

    f32x4 acc[2][4];
#pragma unroll
    for (int rt = 0; rt < 2; ++rt)
#pragma unroll
        for (int ct = 0; ct < 4; ++ct) acc[rt][ct] = {0.f, 0.f, 0.f, 0.f};

#pragma unroll 1
    for (int kc = 0; kc < NC; kc += 64) {
        // W tile [128][64ch] bf16 via direct-to-LDS; inverse-swizzled per-lane source address
#pragma unroll
        for (int q = 0; q < 4; ++q) {
            const int row = q * 32 + srow;
            load_lds16(Wb + (size_t)row * NC + kc + ((sslot ^ (row & 7)) << 3),
                       Ws + (q * 32 + (w << 3)) * 64);
        }
        // x tile: fp32 [64ch][64pos] -> bf16 transposed Xs[pos][ch], swizzled
#pragma unroll
        for (int r = 0; r < 2; ++r) {
            const int idx = r * 256 + t;
            const int cp = idx >> 4;             // channel pair 0..31
            const int p4 = (idx & 15) << 2;      // position base
            const float* xp = &x[((size_t)b * NC + kc + 2 * cp) * NN + n0 + p4];
            const float4 v0 = *(const float4*)xp;
            const float4 v1 = *(const float4*)(xp + NN);
            const float* f0 = (const float*)&v0;
            const float* f1 = (const float*)&v1;
#pragma unroll
            for (int j = 0; j < 4; ++j) {
                const int pos = p4 + j;
                const unsigned u = cvt_pk_bf16(f0[j], f1[j]);  // lo=ch 2cp, hi=ch 2cp+1
                *(unsigned*)&Xs[pos * 64 + ((2 * cp) ^ ((pos & 7) << 3))] = u;
            }
        }
        __syncthreads();
#pragma unroll
        for (int ks = 0; ks < 2; ++ks) {
            s16x8 af[2], bfr[4];
#pragma unroll
            for (int rt = 0; rt < 2; ++rt) {
                const int row = (w << 5) + (rt << 4) + i16;
                af[rt] = *(const s16x8*)&Ws[row * 64 + (((ks << 5) + (g << 3)) ^ ((row & 7) << 3))];
            }
#pragma unroll
            for (int ct = 0; ct < 4; ++ct) {
                const int row = (ct << 4) + i16;
                bfr[ct] = *(const s16x8*)&Xs[row * 64 + (((ks << 5) + (g << 3)) ^ ((row & 7) << 3))];
            }
#pragma unroll
            for (int rt = 0; rt < 2; ++rt)
#pragma unroll
                for (int ct = 0; ct < 4; ++ct)
                    acc[rt][ct] = __builtin_amdgcn_mfma_f32_16x16x32_bf16(af[rt], bfr[ct], acc[rt][ct], 0, 0, 0);
        }
        __syncthreads();
    }

    // ---- epilogue ----
    const bool isK = (w >= 2);
    const int obase = (w & 1) * 32;
    const float* bias = isK ? bk : bq;
    float bv[2][4];
#pragma unroll
    for (int rt = 0; rt < 2; ++rt)
#pragma unroll
        for (int reg = 0; reg < 4; ++reg)
            bv[rt][reg] = bias[obase + rt * 16 + 4 * g + reg];
#pragma unroll
    for (int rt = 0; rt < 2; ++rt)
#pragma unroll
        for (int ct = 0; ct < 4; ++ct)
#pragma unroll
            for (int reg = 0; reg < 4; ++reg) acc[rt][ct][reg] += bv[rt][reg];

    // per-position sum of squares: reduce across g via shuffles, then across wave pairs via LDS
    float sq[4];
#pragma unroll
    for (int ct = 0; ct < 4; ++ct) {
        float s = 0.f;
#pragma unroll
        for (int rt = 0; rt < 2; ++rt)
#pragma unroll
            for (int reg = 0; reg < 4; ++reg) s += acc[rt][ct][reg] * acc[rt][ct][reg];
        s += __shfl_xor(s, 16, 64);
        s += __shfl_xor(s, 32, 64);
        sq[ct] = s;
    }
    ssqL[w][lane] = sq[g];  // slot: ct=g, pos=i16
    __syncthreads();
    const int pairw = (w >> 1) << 1;
    float inv[4];
#pragma unroll
    for (int ct = 0; ct < 4; ++ct) {
        const int p = ct * 16 + i16;
        inv[ct] = rsqrtf(ssqL[pairw][p] + ssqL[pairw + 1][p]);
    }
#pragma unroll
    for (int rt = 0; rt < 2; ++rt)
#pragma unroll
        for (int ct = 0; ct < 4; ++ct)
#pragma unroll
            for (int reg = 0; reg < 4; ++reg) acc[rt][ct][reg] *= inv[ct];

    float* epQ = (float*)WX;                  // [pos][65]
    unsigned short* epK = WX + 8320;          // [o][68]
    if (!isK) {
#pragma unroll
        for (int rt = 0; rt < 2; ++rt)
#pragma unroll
            for (int ct = 0; ct < 4; ++ct)
#pragma unroll
                for (int reg = 0; reg < 4; ++reg)
                    epQ[(ct * 16 + i16) * 65 + (w * 32 + rt * 16 + 4 * g + reg)] = acc[rt][ct][reg];
    } else {
        // ksum over this tile's 64 positions (fp32, pre-quantization)
#pragma unroll
        for (int rt = 0; rt < 2; ++rt)
#pragma unroll
            for (int reg = 0; reg < 4; ++reg) {
                float s = acc[rt][0][reg] + acc[rt][1][reg] + acc[rt][2][reg] + acc[rt][3][reg];
                s += __shfl_xor(s, 1, 64);
                s += __shfl_xor(s, 2, 64);
                s += __shfl_xor(s, 4, 64);
                s += __shfl_xor(s, 8, 64);
                if (i16 == 0) atomicAdd(&ksum[b * NQ + obase + rt * 16 + 4 * g + reg], s);
            }
#pragma unroll
        for (int rt = 0; rt < 2; ++rt)
#pragma unroll
            for (int ct = 0; ct < 4; ++ct)
#pragma unroll
                for (int reg = 0; reg < 4; ++reg)
                    epK[(obase + rt * 16 + 4 * g + reg) * 68 + ct * 16 + i16] = f2bf(acc[rt][ct][reg]);
    }
    __syncthreads();
    // Qt fp32 [o][n] cooperative store
#pragma unroll
    for (int r = 0; r < 4; ++r) {
        const int idx = r * 256 + t;
        const int o = idx >> 4, p4 = (idx & 15) * 4;
        float4 v;
        v.x = epQ[(p4 + 0) * 65 + o];
        v.y = epQ[(p4 + 1) * 65 + o];
        v.z = epQ[(p4 + 2) * 65 + o];
        v.w = epQ[(p4 + 3) * 65 + o];
        *(float4*)&Qt[((size_t)b * NQ + o) * NN + n0 + p4] = v;
    }
    // Kt bf16 [o][n] cooperative store
#pragma unroll
    for (int r = 0; r < 2; ++r) {
        const int idx = r * 256 + t;
        const int o = idx >> 3, s8 = (idx & 7) * 8;
        uint4 pk;
        unsigned short* up = (unsigned short*)&pk;
#pragma unroll
        for (int j = 0; j < 8; ++j) up[j] = epK[o * 68 + s8 + j];
        *(uint4*)&Ktb[((size_t)b * NQ + o) * NN + n0 + s8] = pk;
    }
}

// -------- mat1[b][o][c] += sum_n Kt[o,n]*x[c,n] via bf16 MFMA; xsum[b][c] += sum_n x[c,n] --------
// grid (16 nchunk, 8 ctile, 8 b), block 256 (4 waves). Wave w owns o rows [16w,16w+16).
// A = Kt fragments (k=n contiguous), B = x fragments (converted at staging, same layout, swizzled).
__launch_bounds__(256, 4)
__global__ void kxt_mfma_kernel(const float* __restrict__ x, const unsigned short* __restrict__ Ktb,
                                float* __restrict__ mat1, float* __restrict__ xsum) {
    __shared__ __align__(16) unsigned short Ks[64 * 64];  // [o][n]
    __shared__ __align__(16) unsigned short Xs[64 * 64];  // [c][n]
    const int t = threadIdx.x;
    const int w = t >> 6, lane = t & 63;
    const int g = lane >> 4, i16 = lane & 15;
    const int nch = blockIdx.x, ct0 = blockIdx.y, b = blockIdx.z;
    const int c0 = ct0 * 64;
    const int pbeg = nch * 576;
    const int srow = (w << 3) + (lane >> 3);
    const int sslot = lane & 7;

    f32x4 acc[4];
#pragma unroll
    for (int ct = 0; ct < 4; ++ct) acc[ct] = {0.f, 0.f, 0.f, 0.f};
    float xs4[4] = {0.f, 0.f, 0.f, 0.f};

#pragma unroll 1
    for (int p0 = pbeg; p0 < pbeg + 576; p0 += 64) {
        // Kt tile [64][64] bf16 direct-to-LDS, inverse-swizzled source
#pragma unroll
        for (int q = 0; q < 2; ++q) {
            const int row = q * 32 + srow;
            load_lds16(Ktb + ((size_t)b * NQ + row) * NN + p0 + ((sslot ^ (row & 7)) << 3),
                       Ks + (q * 32 + (w << 3)) * 64);
        }
        // x tile [64c][64n] fp32 -> bf16 (no transpose), swizzled; accumulate xsum pre-conversion
#pragma unroll
        for (int r = 0; r < 4; ++r) {
            const int idx = r * 256 + t;
            const int c = idx >> 4, n4 = (idx & 15) << 2;
            const float4 v = *(const float4*)&x[((size_t)b * NC + c0 + c) * NN + p0 + n4];
            xs4[r] += (v.x + v.y) + (v.z + v.w);
            uint2 u;
            u.x = cvt_pk_bf16(v.x, v.y);
            u.y = cvt_pk_bf16(v.z, v.w);
            *(uint2*)&Xs[c * 64 + (n4 ^ ((c & 7) << 3))] = u;
        }
        __syncthreads();
#pragma unroll
        for (int ks = 0; ks < 2; ++ks) {
            s16x8 a8, b8[4];
            {
                const int row = (w << 4) + i16;
                a8 = *(const s16x8*)&Ks[row * 64 + (((ks << 5) + (g << 3)) ^ ((row & 7) << 3))];
            }
#pragma unroll
            for (int ct = 0; ct < 4; ++ct) {
                const int row = (ct << 4) + i16;
                b8[ct] = *(const s16x8*)&Xs[row * 64 + (((ks << 5) + (g << 3)) ^ ((row & 7) << 3))];
            }
#pragma unroll
            for (int ct = 0; ct < 4; ++ct)
                acc[ct] = __builtin_amdgcn_mfma_f32_16x16x32_bf16(a8, b8[ct], acc[ct], 0, 0, 0);
        }
        __syncthreads();
    }
    // C[m=o][col=c]: row o = 16w + 4g + reg, col c = 16ct + i16 -> coalesced atomic runs
    const int ob = (w << 4) + 4 * g;
#pragma unroll
    for (int ct = 0; ct < 4; ++ct)
#pragma unroll
        for (int reg = 0; reg < 4; ++reg)
            atomicAdd(&mat1[((size_t)b * NQ + ob + reg) * NC + c0 + (ct << 4) + i16], acc[ct][reg]);
#pragma unroll
    for (int r = 0; r < 4; ++r) {
        float s = xs4[r];
        s += __shfl_xor(s, 1, 64);
        s += __shfl_xor(s, 2, 64);
        s += __shfl_xor(s, 4, 64);
        s += __shfl_xor(s, 8, 64);
        if (i16 == 0) atomicAdd(&xsum[b * NC + c0 + r * 16 + (t >> 4)], s);
    }
}

// -------- mat2[b][o][co] = sum_c mat1[o][c]*wv[co][c] + ksum0[o]*bv[co]; vsum --------  (unchanged)
__launch_bounds__(256)
__global__ void mat2_kernel(const float* __restrict__ wv, const float* __restrict__ bv,
                            const float* __restrict__ mat1, const float* __restrict__ ksum,
                            const float* __restrict__ xsum,
                            float* __restrict__ mat2, float* __restrict__ vsum) {
    __shared__ __align__(16) float m1s[64 * 68];  // [o][c]
    __shared__ __align__(16) float wvs[64 * 68];  // [co][c]
    const int t = threadIdx.x;
    const int tx = t & 15, ty = t >> 4;  // co = co0+tx+16jc, o = ty+16jo
    const int ct = blockIdx.x, b = blockIdx.y;
    const int co0 = ct * 64;
    if (t < 64) {
        const int co = co0 + t;
        float s = 0.f;
        for (int c = 0; c < NC; ++c) s += wv[(size_t)co * NC + c] * xsum[b * NC + c];
        vsum[b * NC + co] = s + (float)NN * bv[co];
    }
    float acc[4][4] = {{0.f}};
    for (int cc = 0; cc < NC; cc += 64) {
#pragma unroll 1
        for (int r = 0; r < 4; ++r) {
            const int idx = r * 256 + t;
            const int row = idx >> 4, a = (idx & 15) * 4;
            *(float4*)&m1s[row * 68 + a] = *(const float4*)&mat1[((size_t)b * NQ + row) * NC + cc + a];
            *(float4*)&wvs[row * 68 + a] = *(const float4*)&wv[(size_t)(co0 + row) * NC + cc + a];
        }
        __syncthreads();
#pragma unroll 8
        for (int c4 = 0; c4 < 16; ++c4) {
            float4 mr[4], wr[4];
#pragma unroll
            for (int jo = 0; jo < 4; ++jo) mr[jo] = *(const float4*)&m1s[(ty + 16 * jo) * 68 + c4 * 4];
#pragma unroll
            for (int jc = 0; jc < 4; ++jc) wr[jc] = *(const float4*)&wvs[(tx + 16 * jc) * 68 + c4 * 4];
#pragma unroll
            for (int jo = 0; jo < 4; ++jo)
#pragma unroll
                for (int jc = 0; jc < 4; ++jc)
                    acc[jo][jc] += mr[jo].x * wr[jc].x + mr[jo].y * wr[jc].y +
                                   mr[jo].z * wr[jc].z + mr[jo].w * wr[jc].w;
        }
        __syncthreads();
    }
#pragma unroll
    for (int jo = 0; jo < 4; ++jo) {
        const float ks = ksum[b * NQ + ty + 16 * jo];
#pragma unroll
        for (int jc = 0; jc < 4; ++jc) {
            const int co = co0 + tx + 16 * jc;
            mat2[((size_t)b * NQ + ty + 16 * jo) * NC + co] = acc[jo][jc] + ks * bv[co];
        }
    }
}

// -------- out = x + gamma * (vsum[c] + Qt^T mat2) * tailor --------  (unchanged)
__launch_bounds__(256, 4)
__global__ void final_kernel(const float* __restrict__ x, const float* __restrict__ Qt,
                             const float* __restrict__ ksum, const float* __restrict__ mat2,
                             const float* __restrict__ vsum, const float* __restrict__ gamma,
                             float* __restrict__ out) {
    __shared__ __align__(16) float qs[64 * 64];   // [o][p] stride 64 (global_load_lds)
    __shared__ __align__(16) float m2s[64 * 68];  // [o][c]
    __shared__ float vs[64];
    __shared__ float ksl[64];
    __shared__ float tl[64];
    const int t = threadIdx.x;
    const int a = t & 15, cq = t >> 4;
    const int wid = t >> 6, lane = t & 63;
    const int lrow = lane >> 4, lcol = (lane & 15) * 4;
    const int b = blockIdx.y;
    const int n0 = blockIdx.x * 64;
#pragma unroll
    for (int q = 0; q < 4; ++q) {
        const int o0 = q * 16 + wid * 4;
        load_lds16(Qt + ((size_t)b * NQ + o0 + lrow) * NN + n0 + lcol, &qs[o0 * 64]);
    }
    if (t < 64) ksl[t] = ksum[b * NQ + t] + FEPS;
    __syncthreads();
    if (t < 64) {
        float s = 0.f;
#pragma unroll 8
        for (int o = 0; o < 64; ++o) s += qs[o * 64 + t] * ksl[o];
        tl[t] = 1.0f / ((float)NN + s);
    }
    __syncthreads();
    const float g = gamma[0];
    const float4 tlr = *(const float4*)&tl[a * 4];
    for (int cc = 0; cc < NC; cc += 64) {
#pragma unroll 1
        for (int r = 0; r < 4; ++r) {
            const int idx = r * 256 + t;
            const int o = idx >> 4, a4 = (idx & 15) * 4;
            *(float4*)&m2s[o * 68 + a4] = *(const float4*)&mat2[((size_t)b * NQ + o) * NC + cc + a4];
        }
        if (t < 64) vs[t] = vsum[b * NC + cc + t];
        __syncthreads();
        float acc[4][4];  // [u channel][e position]
#pragma unroll
        for (int u = 0; u < 4; ++u)
#pragma unroll
            for (int e = 0; e < 4; ++e) acc[u][e] = 0.f;
#pragma unroll 8
        for (int o = 0; o < 64; ++o) {
            const float4 qv = *(const float4*)&qs[o * 64 + a * 4];
            const float m0 = m2s[o * 68 + cq];
            const float m1 = m2s[o * 68 + cq + 16];
            const float m2v = m2s[o * 68 + cq + 32];
            const float m3 = m2s[o * 68 + cq + 48];
            acc[0][0] += qv.x * m0; acc[0][1] += qv.y * m0; acc[0][2] += qv.z * m0; acc[0][3] += qv.w * m0;
            acc[1][0] += qv.x * m1; acc[1][1] += qv.y * m1; acc[1][2] += qv.z * m1; acc[1][3] += qv.w * m1;
            acc[2][0] += qv.x * m2v; acc[2][1] += qv.y * m2v; acc[2][2] += qv.z * m2v; acc[2][3] += qv.w * m2v;
            acc[3][0] += qv.x * m3; acc[3][1] += qv.y * m3; acc[3][2] += qv.z * m3; acc[3][3] += qv.w * m3;
        }
#pragma unroll
        for (int u = 0; u < 4; ++u) {
            const int c = cc + cq + 16 * u;
            const size_t gi = ((size_t)b * NC + c) * NN + n0 + a * 4;
            const float4 xv = *(const float4*)&x[gi];
            const float vsv = vs[cq + 16 * u];
            float4 ov;
            ov.x = xv.x + g * (vsv + acc[u][0]) * tlr.x;
            ov.y = xv.y + g * (vsv + acc[u][1]) * tlr.y;
            ov.z = xv.z + g * (vsv + acc[u][2]) * tlr.z;
            ov.w = xv.w + g * (vsv + acc[u][3]) * tlr.w;
            *(float4*)&out[gi] = ov;
        }
        __syncthreads();
    }
}

extern "C" void kernel_launch(void* const* d_in, const int* in_sizes, int n_in,
                              void* d_out, int out_size, void* d_ws, size_t ws_size,
                              hipStream_t stream) {
    (void)in_sizes; (void)n_in; (void)out_size; (void)ws_size;
    const float* x     = (const float*)d_in[0];
    const float* wq    = (const float*)d_in[1];
    const float* bq    = (const float*)d_in[2];
    const float* wk    = (const float*)d_in[3];
    const float* bk    = (const float*)d_in[4];
    const float* wv    = (const float*)d_in[5];
    const float* bv    = (const float*)d_in[6];
    const float* gamma = (const float*)d_in[7];
    float* out = (float*)d_out;
    float* ws  = (float*)d_ws;

    float* Qt            = ws + OFF_Q;
    unsigned short* Ktb  = (unsigned short*)(ws + OFF_KT);
    float* ksum          = ws + OFF_KSUM;
    float* xsum          = ws + OFF_XSUM;
    float* m1            = ws + OFF_M1;
    float* m2            = ws + OFF_M2;
    float* vsum          = ws + OFF_VSUM;
    unsigned short* Wb   = (unsigned short*)(ws + OFF_WB);

    // zero all atomically-accumulated buffers (ksum, xsum, mat1 are contiguous)
    hipMemsetAsync(ksum, 0, (size_t)(NB * NQ + NB * NC + NB * NQ * NC) * sizeof(float), stream);

    prep_w_kernel<<<dim3(16), 256, 0, stream>>>(wq, wk, Wb);
    qk_mfma_kernel<<<dim3(NN / 64, NB), 256, 0, stream>>>(x, Wb, bq, bk, Qt, Ktb, ksum);
    kxt_mfma_kernel<<<dim3(16, 8, NB), 256, 0, stream>>>(x, Ktb, m1, xsum);
    mat2_kernel<<<dim3(8, NB), 256, 0, stream>>>(wv, bv, m1, ksum, xsum, m2, vsum);
    final_kernel<<<dim3(NN / 64, NB), 256, 0, stream>>>(x, Qt, ksum, m2, vsum, gamma, out);
}

// Round 2
// 436.743 us; speedup vs baseline: 1.4144x; 1.0351x over previous
//
#include <hip/hip_runtime.h>

#define NB 8
#define NC 512
#define NQ 64
#define NN 9216
#define FEPS 1e-6f

typedef __attribute__((ext_vector_type(8))) short s16x8;
typedef __attribute__((ext_vector_type(4))) float f32x4;

// workspace layout (floats)
static const size_t OFF_Q    = 0;                                  // Qtb bf16 [B][N][64] swizzled (region sized for fp32, half used)
static const size_t OFF_KT   = OFF_Q + (size_t)NB * NQ * NN;       // Kt bf16 [B][64][N]
static const size_t OFF_KSUM = OFF_KT + (size_t)NB * NQ * NN;      // [B][64]
static const size_t OFF_XSUM = OFF_KSUM + (size_t)NB * NQ;         // [B][512]
static const size_t OFF_M1   = OFF_XSUM + (size_t)NB * NC;         // [B][64][512]
static const size_t OFF_M2   = OFF_M1 + (size_t)NB * NQ * NC;      // m2bT bf16 [B][512][64] swizzled
static const size_t OFF_VSUM = OFF_M2 + (size_t)NB * NQ * NC;      // [B][512]
static const size_t OFF_WB   = OFF_VSUM + (size_t)NB * NC;         // bf16 [128][512]

__device__ __forceinline__ void load_lds16(const void* g, void* l) {
    __builtin_amdgcn_global_load_lds((const __attribute__((address_space(1))) void*)g,
                                     (__attribute__((address_space(3))) void*)l, 16, 0, 0);
}

__device__ __forceinline__ unsigned cvt_pk_bf16(float lo, float hi) {
    unsigned r;
    asm("v_cvt_pk_bf16_f32 %0, %1, %2" : "=v"(r) : "v"(lo), "v"(hi));
    return r;
}

__device__ __forceinline__ unsigned short f2bf(float f) {
    union { float f; unsigned u; } a; a.f = f;
    unsigned r = a.u + 0x7FFFu + ((a.u >> 16) & 1u);
    return (unsigned short)(r >> 16);
}

// -------- one-time weight conversion: Wb[128][512] bf16, rows 0-63 = wq, 64-127 = wk --------
__global__ void prep_w_kernel(const float* __restrict__ wq, const float* __restrict__ wk,
                              unsigned short* __restrict__ Wb) {
    const int idx = blockIdx.x * 256 + threadIdx.x;
#pragma unroll
    for (int k = 0; k < 4; ++k) {
        const int f4 = idx + k * 4096;  // float4 index, 0..16383
        const float* src = (f4 < 8192) ? wq : wk;
        const float4 v = *(const float4*)&src[(size_t)(f4 & 8191) * 4];
        uint2 u;
        u.x = cvt_pk_bf16(v.x, v.y);
        u.y = cvt_pk_bf16(v.z, v.w);
        *(uint2*)&Wb[(size_t)f4 * 4] = u;
    }
}

// -------- Q/K projection via bf16 MFMA + bias + L2 normalize + ksum --------
// grid (144, 8), block 256 (4 waves). Per block: 128 outputs (64 Q + 64 K) x 64 positions.
// Q output: bf16 position-major [n][o], XOR-swizzled (o ^= (n&7)<<3) for final's MFMA fragments.
// K output: bf16 [o][n] for kxt's MFMA fragments.
__launch_bounds__(256, 3)
__global__ void qk_mfma_kernel(const float* __restrict__ x,
                               const unsigned short* __restrict__ Wb,
                               const float* __restrict__ bq, const float* __restrict__ bk,
                               unsigned short* __restrict__ Qtb, unsigned short* __restrict__ Ktb,
                               float* __restrict__ ksum) {
    __shared__ __align__(16) unsigned short WX[12672];  // Ws[128*64] | Xs[64*64]; epilogue: epQb u16[64*64] | epK u16[64*68]
    __shared__ float ssqL[4][64];
    unsigned short* Ws = WX;           // [128][64]
    unsigned short* Xs = WX + 8192;    // [64][64]
    const int t = threadIdx.x;
    const int w = t >> 6, lane = t & 63;
    const int g = lane >> 4, i16 = lane & 15;
    const int b = blockIdx.y;
    const int n0 = blockIdx.x * 64;
    const int srow = (w << 3) + (lane >> 3);
    const int sslot = lane & 7;

    f32x4 acc[2][4];
#pragma unroll
    for (int rt = 0; rt < 2; ++rt)
#pragma unroll
        for (int ct = 0; ct < 4; ++ct) acc[rt][ct] = {0.f, 0.f, 0.f, 0.f};

#pragma unroll 1
    for (int kc = 0; kc < NC; kc += 64) {
        // W tile [128][64ch] bf16 via direct-to-LDS; inverse-swizzled per-lane source address
#pragma unroll
        for (int q = 0; q < 4; ++q) {
            const int row = q * 32 + srow;
            load_lds16(Wb + (size_t)row * NC + kc + ((sslot ^ (row & 7)) << 3),
                       Ws + (q * 32 + (w << 3)) * 64);
        }
        // x tile: fp32 [64ch][64pos] -> bf16 transposed Xs[pos][ch], swizzled
#pragma unroll
        for (int r = 0; r < 2; ++r) {
            const int idx = r * 256 + t;
            const int cp = idx >> 4;             // channel pair 0..31
            const int p4 = (idx & 15) << 2;      // position base
            const float* xp = &x[((size_t)b * NC + kc + 2 * cp) * NN + n0 + p4];
            const float4 v0 = *(const float4*)xp;
            const float4 v1 = *(const float4*)(xp + NN);
            const float* f0 = (const float*)&v0;
            const float* f1 = (const float*)&v1;
#pragma unroll
            for (int j = 0; j < 4; ++j) {
                const int pos = p4 + j;
                const unsigned u = cvt_pk_bf16(f0[j], f1[j]);  // lo=ch 2cp, hi=ch 2cp+1
                *(unsigned*)&Xs[pos * 64 + ((2 * cp) ^ ((pos & 7) << 3))] = u;
            }
        }
        __syncthreads();
#pragma unroll
        for (int ks = 0; ks < 2; ++ks) {
            s16x8 af[2], bfr[4];
#pragma unroll
            for (int rt = 0; rt < 2; ++rt) {
                const int row = (w << 5) + (rt << 4) + i16;
                af[rt] = *(const s16x8*)&Ws[row * 64 + (((ks << 5) + (g << 3)) ^ ((row & 7) << 3))];
            }
#pragma unroll
            for (int ct = 0; ct < 4; ++ct) {
                const int row = (ct << 4) + i16;
                bfr[ct] = *(const s16x8*)&Xs[row * 64 + (((ks << 5) + (g << 3)) ^ ((row & 7) << 3))];
            }
#pragma unroll
            for (int rt = 0; rt < 2; ++rt)
#pragma unroll
                for (int ct = 0; ct < 4; ++ct)
                    acc[rt][ct] = __builtin_amdgcn_mfma_f32_16x16x32_bf16(af[rt], bfr[ct], acc[rt][ct], 0, 0, 0);
        }
        __syncthreads();
    }

    // ---- epilogue ----
    const bool isK = (w >= 2);
    const int obase = (w & 1) * 32;
    const float* bias = isK ? bk : bq;
    float bv[2][4];
#pragma unroll
    for (int rt = 0; rt < 2; ++rt)
#pragma unroll
        for (int reg = 0; reg < 4; ++reg)
            bv[rt][reg] = bias[obase + rt * 16 + 4 * g + reg];
#pragma unroll
    for (int rt = 0; rt < 2; ++rt)
#pragma unroll
        for (int ct = 0; ct < 4; ++ct)
#pragma unroll
            for (int reg = 0; reg < 4; ++reg) acc[rt][ct][reg] += bv[rt][reg];

    // per-position sum of squares: reduce across g via shuffles, then across wave pairs via LDS
    float sq[4];
#pragma unroll
    for (int ct = 0; ct < 4; ++ct) {
        float s = 0.f;
#pragma unroll
        for (int rt = 0; rt < 2; ++rt)
#pragma unroll
            for (int reg = 0; reg < 4; ++reg) s += acc[rt][ct][reg] * acc[rt][ct][reg];
        s += __shfl_xor(s, 16, 64);
        s += __shfl_xor(s, 32, 64);
        sq[ct] = s;
    }
    ssqL[w][lane] = sq[g];  // slot: ct=g, pos=i16
    __syncthreads();
    const int pairw = (w >> 1) << 1;
    float inv[4];
#pragma unroll
    for (int ct = 0; ct < 4; ++ct) {
        const int p = ct * 16 + i16;
        inv[ct] = rsqrtf(ssqL[pairw][p] + ssqL[pairw + 1][p]);
    }
#pragma unroll
    for (int rt = 0; rt < 2; ++rt)
#pragma unroll
        for (int ct = 0; ct < 4; ++ct)
#pragma unroll
            for (int reg = 0; reg < 4; ++reg) acc[rt][ct][reg] *= inv[ct];

    unsigned short* epQb = WX;                // [pos][64] bf16, swizzled
    unsigned short* epK = WX + 8320;          // [o][68]
    if (!isK) {
#pragma unroll
        for (int rt = 0; rt < 2; ++rt)
#pragma unroll
            for (int ct = 0; ct < 4; ++ct)
#pragma unroll
                for (int reg = 0; reg < 4; ++reg) {
                    const int o = w * 32 + rt * 16 + 4 * g + reg;
                    const int pos = ct * 16 + i16;
                    epQb[pos * 64 + (o ^ ((pos & 7) << 3))] = f2bf(acc[rt][ct][reg]);
                }
    } else {
        // ksum over this tile's 64 positions (fp32, pre-quantization)
#pragma unroll
        for (int rt = 0; rt < 2; ++rt)
#pragma unroll
            for (int reg = 0; reg < 4; ++reg) {
                float s = acc[rt][0][reg] + acc[rt][1][reg] + acc[rt][2][reg] + acc[rt][3][reg];
                s += __shfl_xor(s, 1, 64);
                s += __shfl_xor(s, 2, 64);
                s += __shfl_xor(s, 4, 64);
                s += __shfl_xor(s, 8, 64);
                if (i16 == 0) atomicAdd(&ksum[b * NQ + obase + rt * 16 + 4 * g + reg], s);
            }
#pragma unroll
        for (int rt = 0; rt < 2; ++rt)
#pragma unroll
            for (int ct = 0; ct < 4; ++ct)
#pragma unroll
                for (int reg = 0; reg < 4; ++reg)
                    epK[(obase + rt * 16 + 4 * g + reg) * 68 + ct * 16 + i16] = f2bf(acc[rt][ct][reg]);
    }
    __syncthreads();
    // Qtb [n][o] (pre-swizzled) linear copy: 4096 ushorts = 512 uint4
    {
        const size_t base = ((size_t)b * NN + n0) * 64;
        const uint4* src = (const uint4*)epQb;
#pragma unroll
        for (int r = 0; r < 2; ++r) {
            const int idx = r * 256 + t;
            *(uint4*)&Qtb[base + (size_t)idx * 8] = src[idx];
        }
    }
    // Kt bf16 [o][n] cooperative store
#pragma unroll
    for (int r = 0; r < 2; ++r) {
        const int idx = r * 256 + t;
        const int o = idx >> 3, s8 = (idx & 7) * 8;
        uint4 pk;
        unsigned short* up = (unsigned short*)&pk;
#pragma unroll
        for (int j = 0; j < 8; ++j) up[j] = epK[o * 68 + s8 + j];
        *(uint4*)&Ktb[((size_t)b * NQ + o) * NN + n0 + s8] = pk;
    }
}

// -------- mat1[b][o][c] += sum_n Kt[o,n]*x[c,n] via bf16 MFMA; xsum[b][c] += sum_n x[c,n] --------
__launch_bounds__(256, 4)
__global__ void kxt_mfma_kernel(const float* __restrict__ x, const unsigned short* __restrict__ Ktb,
                                float* __restrict__ mat1, float* __restrict__ xsum) {
    __shared__ __align__(16) unsigned short Ks[64 * 64];  // [o][n]
    __shared__ __align__(16) unsigned short Xs[64 * 64];  // [c][n]
    const int t = threadIdx.x;
    const int w = t >> 6, lane = t & 63;
    const int g = lane >> 4, i16 = lane & 15;
    const int nch = blockIdx.x, ct0 = blockIdx.y, b = blockIdx.z;
    const int c0 = ct0 * 64;
    const int pbeg = nch * 576;
    const int srow = (w << 3) + (lane >> 3);
    const int sslot = lane & 7;

    f32x4 acc[4];
#pragma unroll
    for (int ct = 0; ct < 4; ++ct) acc[ct] = {0.f, 0.f, 0.f, 0.f};
    float xs4[4] = {0.f, 0.f, 0.f, 0.f};

#pragma unroll 1
    for (int p0 = pbeg; p0 < pbeg + 576; p0 += 64) {
#pragma unroll
        for (int q = 0; q < 2; ++q) {
            const int row = q * 32 + srow;
            load_lds16(Ktb + ((size_t)b * NQ + row) * NN + p0 + ((sslot ^ (row & 7)) << 3),
                       Ks + (q * 32 + (w << 3)) * 64);
        }
#pragma unroll
        for (int r = 0; r < 4; ++r) {
            const int idx = r * 256 + t;
            const int c = idx >> 4, n4 = (idx & 15) << 2;
            const float4 v = *(const float4*)&x[((size_t)b * NC + c0 + c) * NN + p0 + n4];
            xs4[r] += (v.x + v.y) + (v.z + v.w);
            uint2 u;
            u.x = cvt_pk_bf16(v.x, v.y);
            u.y = cvt_pk_bf16(v.z, v.w);
            *(uint2*)&Xs[c * 64 + (n4 ^ ((c & 7) << 3))] = u;
        }
        __syncthreads();
#pragma unroll
        for (int ks = 0; ks < 2; ++ks) {
            s16x8 a8, b8[4];
            {
                const int row = (w << 4) + i16;
                a8 = *(const s16x8*)&Ks[row * 64 + (((ks << 5) + (g << 3)) ^ ((row & 7) << 3))];
            }
#pragma unroll
            for (int ct = 0; ct < 4; ++ct) {
                const int row = (ct << 4) + i16;
                b8[ct] = *(const s16x8*)&Xs[row * 64 + (((ks << 5) + (g << 3)) ^ ((row & 7) << 3))];
            }
#pragma unroll
            for (int ct = 0; ct < 4; ++ct)
                acc[ct] = __builtin_amdgcn_mfma_f32_16x16x32_bf16(a8, b8[ct], acc[ct], 0, 0, 0);
        }
        __syncthreads();
    }
    const int ob = (w << 4) + 4 * g;
#pragma unroll
    for (int ct = 0; ct < 4; ++ct)
#pragma unroll
        for (int reg = 0; reg < 4; ++reg)
            atomicAdd(&mat1[((size_t)b * NQ + ob + reg) * NC + c0 + (ct << 4) + i16], acc[ct][reg]);
#pragma unroll
    for (int r = 0; r < 4; ++r) {
        float s = xs4[r];
        s += __shfl_xor(s, 1, 64);
        s += __shfl_xor(s, 2, 64);
        s += __shfl_xor(s, 4, 64);
        s += __shfl_xor(s, 8, 64);
        if (i16 == 0) atomicAdd(&xsum[b * NC + c0 + r * 16 + (t >> 4)], s);
    }
}

// -------- m2bT[b][co][o] (bf16, swizzled) = sum_c mat1[o][c]*wv[co][c] + ksum0[o]*bv[co]; vsum --------
__launch_bounds__(256)
__global__ void mat2_kernel(const float* __restrict__ wv, const float* __restrict__ bv,
                            const float* __restrict__ mat1, const float* __restrict__ ksum,
                            const float* __restrict__ xsum,
                            unsigned short* __restrict__ m2bT, float* __restrict__ vsum) {
    __shared__ __align__(16) float m1s[64 * 68];  // [o][c]
    __shared__ __align__(16) float wvs[64 * 68];  // [co][c]
    const int t = threadIdx.x;
    const int tx = t & 15, ty = t >> 4;  // co = co0+tx+16jc, o = ty+16jo
    const int ct = blockIdx.x, b = blockIdx.y;
    const int co0 = ct * 64;
    if (t < 64) {
        const int co = co0 + t;
        float s = 0.f;
        for (int c = 0; c < NC; ++c) s += wv[(size_t)co * NC + c] * xsum[b * NC + c];
        vsum[b * NC + co] = s + (float)NN * bv[co];
    }
    float acc[4][4] = {{0.f}};
    for (int cc = 0; cc < NC; cc += 64) {
#pragma unroll 1
        for (int r = 0; r < 4; ++r) {
            const int idx = r * 256 + t;
            const int row = idx >> 4, a = (idx & 15) * 4;
            *(float4*)&m1s[row * 68 + a] = *(const float4*)&mat1[((size_t)b * NQ + row) * NC + cc + a];
            *(float4*)&wvs[row * 68 + a] = *(const float4*)&wv[(size_t)(co0 + row) * NC + cc + a];
        }
        __syncthreads();
#pragma unroll 8
        for (int c4 = 0; c4 < 16; ++c4) {
            float4 mr[4], wr[4];
#pragma unroll
            for (int jo = 0; jo < 4; ++jo) mr[jo] = *(const float4*)&m1s[(ty + 16 * jo) * 68 + c4 * 4];
#pragma unroll
            for (int jc = 0; jc < 4; ++jc) wr[jc] = *(const float4*)&wvs[(tx + 16 * jc) * 68 + c4 * 4];
#pragma unroll
            for (int jo = 0; jo < 4; ++jo)
#pragma unroll
                for (int jc = 0; jc < 4; ++jc)
                    acc[jo][jc] += mr[jo].x * wr[jc].x + mr[jo].y * wr[jc].y +
                                   mr[jo].z * wr[jc].z + mr[jo].w * wr[jc].w;
        }
        __syncthreads();
    }
#pragma unroll
    for (int jo = 0; jo < 4; ++jo) {
        const float ks = ksum[b * NQ + ty + 16 * jo];
        const int o = ty + 16 * jo;
#pragma unroll
        for (int jc = 0; jc < 4; ++jc) {
            const int co = co0 + tx + 16 * jc;
            m2bT[((size_t)b * NC + co) * NQ + (o ^ ((co & 7) << 3))] = f2bf(acc[jo][jc] + ks * bv[co]);
        }
    }
}

// -------- out = x + gamma * (vsum[c] + Qt^T mat2) * tailor, via bf16 MFMA --------
// grid (144, 8), block 256 (4 waves). A = Q [m=pos][k=o], B = m2T [n=c][k=o].
// C layout: col = c = lane&15, row = pos = 4*(lane>>4)+reg. Wave w owns c sub-tile w of each 64-c chunk.
__launch_bounds__(256, 4)
__global__ void final_mfma_kernel(const float* __restrict__ x, const unsigned short* __restrict__ Qtb,
                                  const float* __restrict__ ksum, const unsigned short* __restrict__ m2bT,
                                  const float* __restrict__ vsum, const float* __restrict__ gamma,
                                  float* __restrict__ out) {
    __shared__ __align__(16) unsigned short Qs[64 * 64];     // [pos][o] swizzled, 8 KB
    __shared__ __align__(16) unsigned short Ms[2][64 * 64];  // [c][o] swizzled, 2 x 8 KB
    __shared__ float vsall[512];
    __shared__ float ksl[64];
    __shared__ float tl[64];
    const int t = threadIdx.x;
    const int w = t >> 6, lane = t & 63;
    const int g = lane >> 4, i16 = lane & 15;
    const int b = blockIdx.y;
    const int n0 = blockIdx.x * 64;

    const unsigned short* qg = Qtb + ((size_t)b * NN + n0) * 64;
    const unsigned short* mg = m2bT + (size_t)b * NC * 64;
    // stage Q tile (8 KB) + first m2 chunk (8 KB)
#pragma unroll
    for (int r = 0; r < 2; ++r) {
        const int off = (w * 2 + r) * 512;  // ushort offset, wave-uniform
        load_lds16(qg + off + lane * 8, Qs + off);
        load_lds16(mg + off + lane * 8, &Ms[0][off]);
    }
    vsall[t] = vsum[b * NC + t];
    vsall[256 + t] = vsum[b * NC + 256 + t];
    if (t < 64) ksl[t] = ksum[b * NQ + t] + FEPS;
    __syncthreads();  // drains vmcnt: Qs + Ms[0] ready
    // tailor per position (bf16 Q, consistent with MFMA operand)
    if (t < 64) {
        float s = 0.f;
        const int sw = (t & 7) << 3;
#pragma unroll 8
        for (int o = 0; o < 64; ++o) {
            union { unsigned u; float f; } cv;
            cv.u = (unsigned)Qs[t * 64 + o] << 16;
            s += cv.f * ksl[o ^ sw];
        }
        tl[t] = 1.0f / ((float)NN + s);
    }
    // hoist A fragments (Q) — Qs is ready and never overwritten
    s16x8 af[4][2];
#pragma unroll
    for (int mt = 0; mt < 4; ++mt)
#pragma unroll
        for (int ks = 0; ks < 2; ++ks) {
            const int row = mt * 16 + i16;
            af[mt][ks] = *(const s16x8*)&Qs[row * 64 + (((ks << 5) + (g << 3)) ^ ((row & 7) << 3))];
        }
    const float gm = gamma[0];
    const int c_local = w * 16 + i16;
    __syncthreads();  // tl visible

#pragma unroll 1
    for (int cc8 = 0; cc8 < 8; ++cc8) {
        if (cc8 < 7) {  // prefetch next chunk into the other buffer
#pragma unroll
            for (int r = 0; r < 2; ++r) {
                const int off = (w * 2 + r) * 512;
                load_lds16(mg + (cc8 + 1) * 4096 + off + lane * 8, &Ms[(cc8 + 1) & 1][off]);
            }
        }
        const unsigned short* mbuf = Ms[cc8 & 1];
        s16x8 b8[2];
#pragma unroll
        for (int ks = 0; ks < 2; ++ks)
            b8[ks] = *(const s16x8*)&mbuf[c_local * 64 + (((ks << 5) + (g << 3)) ^ ((i16 & 7) << 3))];
        f32x4 acc[4];
#pragma unroll
        for (int mt = 0; mt < 4; ++mt) acc[mt] = {0.f, 0.f, 0.f, 0.f};
#pragma unroll
        for (int ks = 0; ks < 2; ++ks)
#pragma unroll
            for (int mt = 0; mt < 4; ++mt)
                acc[mt] = __builtin_amdgcn_mfma_f32_16x16x32_bf16(af[mt][ks], b8[ks], acc[mt], 0, 0, 0);
        // epilogue: out = x + gm*(vsum + acc)*tl
        const int c = cc8 * 64 + c_local;
        const float vsv = vsall[c];
        const size_t rowbase = ((size_t)b * NC + c) * NN + n0;
#pragma unroll
        for (int mt = 0; mt < 4; ++mt) {
            const int p = mt * 16 + 4 * g;
            const float4 xv = *(const float4*)&x[rowbase + p];
            const float4 t4 = *(const float4*)&tl[p];
            float4 ov;
            ov.x = xv.x + gm * (vsv + acc[mt][0]) * t4.x;
            ov.y = xv.y + gm * (vsv + acc[mt][1]) * t4.y;
            ov.z = xv.z + gm * (vsv + acc[mt][2]) * t4.z;
            ov.w = xv.w + gm * (vsv + acc[mt][3]) * t4.w;
            *(float4*)&out[rowbase + p] = ov;
        }
        __syncthreads();  // drain prefetch + protect buffer reuse
    }
}

extern "C" void kernel_launch(void* const* d_in, const int* in_sizes, int n_in,
                              void* d_out, int out_size, void* d_ws, size_t ws_size,
                              hipStream_t stream) {
    (void)in_sizes; (void)n_in; (void)out_size; (void)ws_size;
    const float* x     = (const float*)d_in[0];
    const float* wq    = (const float*)d_in[1];
    const float* bq    = (const float*)d_in[2];
    const float* wk    = (const float*)d_in[3];
    const float* bk    = (const float*)d_in[4];
    const float* wv    = (const float*)d_in[5];
    const float* bv    = (const float*)d_in[6];
    const float* gamma = (const float*)d_in[7];
    float* out = (float*)d_out;
    float* ws  = (float*)d_ws;

    unsigned short* Qtb  = (unsigned short*)(ws + OFF_Q);
    unsigned short* Ktb  = (unsigned short*)(ws + OFF_KT);
    float* ksum          = ws + OFF_KSUM;
    float* xsum          = ws + OFF_XSUM;
    float* m1            = ws + OFF_M1;
    unsigned short* m2b  = (unsigned short*)(ws + OFF_M2);
    float* vsum          = ws + OFF_VSUM;
    unsigned short* Wb   = (unsigned short*)(ws + OFF_WB);

    // zero all atomically-accumulated buffers (ksum, xsum, mat1 are contiguous)
    hipMemsetAsync(ksum, 0, (size_t)(NB * NQ + NB * NC + NB * NQ * NC) * sizeof(float), stream);

    prep_w_kernel<<<dim3(16), 256, 0, stream>>>(wq, wk, Wb);
    qk_mfma_kernel<<<dim3(NN / 64, NB), 256, 0, stream>>>(x, Wb, bq, bk, Qtb, Ktb, ksum);
    kxt_mfma_kernel<<<dim3(16, 8, NB), 256, 0, stream>>>(x, Ktb, m1, xsum);
    mat2_kernel<<<dim3(8, NB), 256, 0, stream>>>(wv, bv, m1, ksum, xsum, m2b, vsum);
    final_mfma_kernel<<<dim3(NN / 64, NB), 256, 0, stream>>>(x, Qtb, ksum, m2b, vsum, gamma, out);
}